// Round 2
// baseline (891.908 us; speedup 1.0000x reference)
//
#include <hip/hip_runtime.h>
#include <math.h>

#define B_ 64
#define N_ 4096
#define D_ 128
#define S_ 7
#define H_ 256
#define ITERS_ 3
#define AP 132  // padded LDS row stride (132*4B = 528B, 16B-aligned, breaks 128-stride bank conflicts)

__device__ __forceinline__ float dot4(float4 a, float4 b) {
  return a.x * b.x + a.y * b.y + a.z * b.z + a.w * b.w;
}
__device__ __forceinline__ float4 ld4(const float* p) {
  return *reinterpret_cast<const float4*>(p);
}

// ---------------- K0: slots = mu + sigma * noise ----------------
__global__ void k_init(const float* __restrict__ noise, const float* __restrict__ mu,
                       const float* __restrict__ sigma, float* __restrict__ slots) {
  int idx = blockIdx.x * 256 + threadIdx.x;  // 57344 total
  int d = idx & 127;
  slots[idx] = mu[d] + sigma[d] * noise[idx];
}

// ---------------- K1: LN(emb), keys = ln@Wk^T+bk, values = ln@Wv^T+bv ----------------
// 64 rows/block, 256 threads. GEMM: thread = (col-group of 4, row-group of 16).
// A-tile reads are wave-uniform LDS broadcasts: 1 ds_read_b128 -> 16 v_fmac.
__global__ __launch_bounds__(256) void k_lnkv(
    const float* __restrict__ emb,
    const float* __restrict__ Wk, const float* __restrict__ bk,
    const float* __restrict__ Wv, const float* __restrict__ bv,
    const float* __restrict__ lng, const float* __restrict__ lnb,
    float* __restrict__ keys, float* __restrict__ values) {
  __shared__ __align__(16) float a[64 * AP];
  int t = threadIdx.x;
  long rowbase = (long)blockIdx.x * 64;

  // stage + LN: 4 threads per row, 32 elems each
  {
    int r = t >> 2;
    int io = (t & 3) * 32;
    const float* src = emb + (rowbase + r) * D_ + io;
    float4 xv[8];
    float sum = 0.f, sumsq = 0.f;
#pragma unroll
    for (int k = 0; k < 8; k++) {
      xv[k] = reinterpret_cast<const float4*>(src)[k];
      sum += xv[k].x + xv[k].y + xv[k].z + xv[k].w;
      sumsq += xv[k].x * xv[k].x + xv[k].y * xv[k].y + xv[k].z * xv[k].z + xv[k].w * xv[k].w;
    }
    sum += __shfl_xor(sum, 1, 4);   sum += __shfl_xor(sum, 2, 4);
    sumsq += __shfl_xor(sumsq, 1, 4); sumsq += __shfl_xor(sumsq, 2, 4);
    float mean = sum * (1.f / 128.f);
    float var = sumsq * (1.f / 128.f) - mean * mean;
    float rs = rsqrtf(var + 1e-5f);
#pragma unroll
    for (int k = 0; k < 8; k++) {
      float4 gv = reinterpret_cast<const float4*>(lng + io)[k];
      float4 bv4 = reinterpret_cast<const float4*>(lnb + io)[k];
      float4 o;
      o.x = (xv[k].x - mean) * rs * gv.x + bv4.x;
      o.y = (xv[k].y - mean) * rs * gv.y + bv4.y;
      o.z = (xv[k].z - mean) * rs * gv.z + bv4.z;
      o.w = (xv[k].w - mean) * rs * gv.w + bv4.w;
      *reinterpret_cast<float4*>(&a[r * AP + io + k * 4]) = o;
    }
  }
  __syncthreads();

  // GEMM phase
  int cg = t & 63;   // column group (wave lanes) -> broadcast A reads
  int rg = t >> 6;   // row group (wave id)
  const float* W; const float* bias; float* dst; int c0;
  if (cg < 32) { W = Wk; bias = bk; dst = keys;   c0 = cg * 4; }
  else         { W = Wv; bias = bv; dst = values; c0 = (cg - 32) * 4; }
  const float* w0 = W + c0 * D_;

  float acc[16][4];
#pragma unroll
  for (int rr = 0; rr < 16; rr++)
#pragma unroll
    for (int c = 0; c < 4; c++) acc[rr][c] = 0.f;

  for (int i4 = 0; i4 < D_; i4 += 4) {
    float4 wA = ld4(w0 + i4);
    float4 wB = ld4(w0 + D_ + i4);
    float4 wC = ld4(w0 + 2 * D_ + i4);
    float4 wD = ld4(w0 + 3 * D_ + i4);
#pragma unroll
    for (int rr = 0; rr < 16; rr++) {
      float4 av = *reinterpret_cast<const float4*>(&a[(rg * 16 + rr) * AP + i4]);
      acc[rr][0] += dot4(av, wA);
      acc[rr][1] += dot4(av, wB);
      acc[rr][2] += dot4(av, wC);
      acc[rr][3] += dot4(av, wD);
    }
  }
  float b0 = bias[c0], b1_ = bias[c0 + 1], b2_ = bias[c0 + 2], b3 = bias[c0 + 3];
#pragma unroll
  for (int rr = 0; rr < 16; rr++) {
    float4 o = make_float4(acc[rr][0] + b0, acc[rr][1] + b1_, acc[rr][2] + b2_, acc[rr][3] + b3);
    *reinterpret_cast<float4*>(&dst[(rowbase + rg * 16 + rr) * D_ + c0]) = o;
  }
}

// ---------------- K2: q = LN(slots) @ Wq^T + bq ----------------
__global__ __launch_bounds__(128) void k_q(
    const float* __restrict__ slots, const float* __restrict__ Wq, const float* __restrict__ bq,
    const float* __restrict__ g, const float* __restrict__ b, float* __restrict__ q) {
  __shared__ __align__(16) float lns[AP];
  __shared__ float red[4];
  int row = blockIdx.x;  // b*7+s
  int d = threadIdx.x;
  float x = slots[row * D_ + d];
  float s1 = x, s2 = x * x;
#pragma unroll
  for (int off = 32; off >= 1; off >>= 1) { s1 += __shfl_down(s1, off); s2 += __shfl_down(s2, off); }
  if ((d & 63) == 0) { red[(d >> 6) * 2] = s1; red[(d >> 6) * 2 + 1] = s2; }
  __syncthreads();
  float sum = red[0] + red[2], sumsq = red[1] + red[3];
  float mean = sum * (1.f / 128.f);
  float var = sumsq * (1.f / 128.f) - mean * mean;
  float rs = rsqrtf(var + 1e-5f);
  lns[d] = (x - mean) * rs * g[d] + b[d];
  __syncthreads();
  const float* w = Wq + d * D_;
  float acc = bq[d];
  for (int i4 = 0; i4 < D_; i4 += 4) acc += dot4(*reinterpret_cast<const float4*>(&lns[i4]), ld4(w + i4));
  q[row * D_ + d] = acc;
}

// ---------------- K3a: logits[b][s][j] = q[b,s,:] . keys[b,j,:] ----------------
// grid: 64 b * 8 j-chunks of 512; keys read exactly once per iteration.
__global__ __launch_bounds__(256) void k_logits(
    const float* __restrict__ qbuf, const float* __restrict__ keys, float* __restrict__ logits) {
  __shared__ __align__(16) float qs[7 * AP];
  __shared__ __align__(16) float kt[64 * AP];
  __shared__ float red[28 * 64];  // [g*7+s][j]
  int t = threadIdx.x;
  int b = blockIdx.x >> 3, jc = blockIdx.x & 7;
  if (t < 224) {
    int s = t >> 5, i4 = (t & 31) * 4;
    *reinterpret_cast<float4*>(&qs[s * AP + i4]) =
        ld4(&qbuf[(b * 7 + s) * D_ + i4]);
  }
  int j = t & 63, g = t >> 6, ib = g * 32;
  for (int sub = 0; sub < 8; sub++) {
    int j0 = jc * 512 + sub * 64;
#pragma unroll
    for (int u = 0; u < 8; u++) {
      int f = u * 256 + t;
      int row = f >> 5, i4 = (f & 31) * 4;
      *reinterpret_cast<float4*>(&kt[row * AP + i4]) =
          ld4(&keys[((long)b * N_ + j0 + row) * D_ + i4]);
    }
    __syncthreads();
    float acc7[7];
#pragma unroll
    for (int s = 0; s < 7; s++) acc7[s] = 0.f;
#pragma unroll
    for (int st = 0; st < 8; st++) {
      float4 kv = *reinterpret_cast<const float4*>(&kt[j * AP + ib + st * 4]);
#pragma unroll
      for (int s = 0; s < 7; s++) {
        float4 qv = *reinterpret_cast<const float4*>(&qs[s * AP + ib + st * 4]);
        acc7[s] += dot4(kv, qv);
      }
    }
#pragma unroll
    for (int s = 0; s < 7; s++) red[(g * 7 + s) * 64 + j] = acc7[s];
    __syncthreads();
    // 448 work items, 256 threads -> strided loop (was `if (t<448)`: dropped s>=4. BUG FIX R1)
    for (int pp = t; pp < 448; pp += 256) {
      int s = pp >> 6, jj = pp & 63;
      float l = red[s * 64 + jj] + red[(7 + s) * 64 + jj] +
                red[(14 + s) * 64 + jj] + red[(21 + s) * 64 + jj];
      logits[(long)(b * 7 + s) * N_ + j0 + jj] = l;
    }
    __syncthreads();
  }
}

// ---------------- K3b: softmax over N, in place ----------------
// NOTE: reference's (softmax+1e-8)/renorm is a <=4.1e-5 relative perturbation -> skipped.
__global__ __launch_bounds__(256) void k_softmax(float* __restrict__ logits) {
  __shared__ float sm[4], ss[4];
  long base = (long)blockIdx.x * N_;
  int t = threadIdx.x;
  float4 v[4];
  float lmax = -1e30f;
#pragma unroll
  for (int p = 0; p < 4; p++) {
    v[p] = ld4(&logits[base + (p * 256 + t) * 4]);
    lmax = fmaxf(lmax, fmaxf(fmaxf(v[p].x, v[p].y), fmaxf(v[p].z, v[p].w)));
  }
#pragma unroll
  for (int off = 32; off >= 1; off >>= 1) lmax = fmaxf(lmax, __shfl_down(lmax, off));
  if ((t & 63) == 0) sm[t >> 6] = lmax;
  __syncthreads();
  float m = fmaxf(fmaxf(sm[0], sm[1]), fmaxf(sm[2], sm[3]));
  float lsum = 0.f;
#pragma unroll
  for (int p = 0; p < 4; p++) {
    v[p].x = __expf(v[p].x - m); v[p].y = __expf(v[p].y - m);
    v[p].z = __expf(v[p].z - m); v[p].w = __expf(v[p].w - m);
    lsum += v[p].x + v[p].y + v[p].z + v[p].w;
  }
#pragma unroll
  for (int off = 32; off >= 1; off >>= 1) lsum += __shfl_down(lsum, off);
  if ((t & 63) == 0) ss[t >> 6] = lsum;
  __syncthreads();
  float inv = 1.f / (ss[0] + ss[1] + ss[2] + ss[3]);
#pragma unroll
  for (int p = 0; p < 4; p++) {
    v[p].x *= inv; v[p].y *= inv; v[p].z *= inv; v[p].w *= inv;
    *reinterpret_cast<float4*>(&logits[base + (p * 256 + t) * 4]) = v[p];
  }
}

// ---------------- K3c: partialA[b][jc][s][d] = sum_{j in chunk} p[b,s,j] * values[b,j,d] ----------------
__global__ __launch_bounds__(256) void k_updates(
    const float* __restrict__ p, const float* __restrict__ values, float* __restrict__ partialA) {
  __shared__ __align__(16) float vt[64 * AP];  // reused as red[8][7][128] at the end (7168 <= 8448)
  __shared__ float pt[7 * 64];
  int t = threadIdx.x;
  int b = blockIdx.x >> 3, jc = blockIdx.x & 7;
  int d4 = (t & 31) * 4, jg = t >> 5;
  float acc[7][4];
#pragma unroll
  for (int s = 0; s < 7; s++)
#pragma unroll
    for (int c = 0; c < 4; c++) acc[s][c] = 0.f;

  for (int sub = 0; sub < 8; sub++) {
    int j0 = jc * 512 + sub * 64;
#pragma unroll
    for (int u = 0; u < 8; u++) {
      int f = u * 256 + t;
      int row = f >> 5, i4 = (f & 31) * 4;
      *reinterpret_cast<float4*>(&vt[row * AP + i4]) =
          ld4(&values[((long)b * N_ + j0 + row) * D_ + i4]);
    }
    // 448 work items, 256 threads -> strided loop (was `if (t<448)`: s>=4 read garbage. BUG FIX R1)
    for (int pp = t; pp < 448; pp += 256) {
      int s = pp >> 6, jj = pp & 63;
      pt[s * 64 + jj] = p[(long)(b * 7 + s) * N_ + j0 + jj];
    }
    __syncthreads();
#pragma unroll
    for (int jl = 0; jl < 8; jl++) {
      int jj = jg * 8 + jl;
      float4 vv = *reinterpret_cast<const float4*>(&vt[jj * AP + d4]);
#pragma unroll
      for (int s = 0; s < 7; s++) {
        float e = pt[s * 64 + jj];
        acc[s][0] += e * vv.x; acc[s][1] += e * vv.y;
        acc[s][2] += e * vv.z; acc[s][3] += e * vv.w;
      }
    }
    __syncthreads();
  }
  float* red = vt;
#pragma unroll
  for (int s = 0; s < 7; s++)
    *reinterpret_cast<float4*>(&red[(jg * 7 + s) * 128 + d4]) =
        make_float4(acc[s][0], acc[s][1], acc[s][2], acc[s][3]);
  __syncthreads();
  for (int pp = t; pp < 896; pp += 256) {
    int s = pp >> 7, d = pp & 127;
    float x = 0.f;
#pragma unroll
    for (int g = 0; g < 8; g++) x += red[(g * 7 + s) * 128 + d];
    partialA[((long)(b * 8 + jc) * 7 + s) * 128 + d] = x;
  }
}

// ---------------- K4: combine partials + GRUCell + LN + FFN (+residual), in-place on slots ----------------
__global__ __launch_bounds__(128) void k_gruff(
    const float* __restrict__ partialA, float* __restrict__ slots,
    const float* __restrict__ Wih, const float* __restrict__ Whh,
    const float* __restrict__ bih, const float* __restrict__ bhh,
    const float* __restrict__ W1, const float* __restrict__ b1,
    const float* __restrict__ W2, const float* __restrict__ b2,
    const float* __restrict__ gff, const float* __restrict__ bff) {
  __shared__ __align__(16) float xs[AP];
  __shared__ __align__(16) float hs[AP];
  __shared__ __align__(16) float lns[AP];
  __shared__ __align__(16) float h1s[H_];
  __shared__ float red4[4];
  int blk = blockIdx.x;
  int b = blk / 7, s = blk % 7;
  int d = threadIdx.x;

  float x = 0.f;
#pragma unroll
  for (int jc = 0; jc < 8; jc++) x += partialA[((long)(b * 8 + jc) * 7 + s) * 128 + d];
  float h = slots[blk * D_ + d];
  xs[d] = x; hs[d] = h;
  __syncthreads();

  float gir = bih[d], giz = bih[128 + d], gin = bih[256 + d];
  float ghr = bhh[d], ghz = bhh[128 + d], ghn = bhh[256 + d];
  const float* wir = Wih + d * D_;
  const float* wiz = Wih + (128 + d) * D_;
  const float* win = Wih + (256 + d) * D_;
  const float* whr = Whh + d * D_;
  const float* whz = Whh + (128 + d) * D_;
  const float* whn = Whh + (256 + d) * D_;
  for (int i4 = 0; i4 < D_; i4 += 4) {
    float4 xv = *reinterpret_cast<const float4*>(&xs[i4]);
    float4 hv = *reinterpret_cast<const float4*>(&hs[i4]);
    gir += dot4(xv, ld4(wir + i4)); giz += dot4(xv, ld4(wiz + i4)); gin += dot4(xv, ld4(win + i4));
    ghr += dot4(hv, ld4(whr + i4)); ghz += dot4(hv, ld4(whz + i4)); ghn += dot4(hv, ld4(whn + i4));
  }
  float r = 1.f / (1.f + __expf(-(gir + ghr)));
  float z = 1.f / (1.f + __expf(-(giz + ghz)));
  float n = tanhf(gin + r * ghn);
  float ns = (1.f - z) * n + z * h;

  // LN over the new slot row
  float s1 = ns, s2 = ns * ns;
#pragma unroll
  for (int off = 32; off >= 1; off >>= 1) { s1 += __shfl_down(s1, off); s2 += __shfl_down(s2, off); }
  if ((d & 63) == 0) { red4[(d >> 6) * 2] = s1; red4[(d >> 6) * 2 + 1] = s2; }
  __syncthreads();
  float sum = red4[0] + red4[2], sumsq = red4[1] + red4[3];
  float mean = sum * (1.f / 128.f);
  float var = sumsq * (1.f / 128.f) - mean * mean;
  float rs = rsqrtf(var + 1e-5f);
  lns[d] = (ns - mean) * rs * gff[d] + bff[d];
  __syncthreads();

  float a0 = b1[d], a1 = b1[d + 128];
  const float* w1a = W1 + d * D_;
  const float* w1b = W1 + (128 + d) * D_;
  for (int i4 = 0; i4 < D_; i4 += 4) {
    float4 lv = *reinterpret_cast<const float4*>(&lns[i4]);
    a0 += dot4(lv, ld4(w1a + i4));
    a1 += dot4(lv, ld4(w1b + i4));
  }
  h1s[d] = fmaxf(a0, 0.f);
  h1s[d + 128] = fmaxf(a1, 0.f);
  __syncthreads();

  float f = b2[d];
  const float* w2r = W2 + d * H_;
  for (int h4 = 0; h4 < H_; h4 += 4)
    f += dot4(*reinterpret_cast<const float4*>(&h1s[h4]), ld4(w2r + h4));
  slots[blk * D_ + d] = ns + f;
}

extern "C" void kernel_launch(void* const* d_in, const int* in_sizes, int n_in,
                              void* d_out, int out_size, void* d_ws, size_t ws_size,
                              hipStream_t stream) {
  const float* emb   = (const float*)d_in[0];
  const float* noise = (const float*)d_in[1];
  const float* mu    = (const float*)d_in[2];
  const float* sigma = (const float*)d_in[3];
  const float* Wk = (const float*)d_in[4];  const float* bk = (const float*)d_in[5];
  const float* Wq = (const float*)d_in[6];  const float* bq = (const float*)d_in[7];
  const float* Wv = (const float*)d_in[8];  const float* bv = (const float*)d_in[9];
  const float* Wih = (const float*)d_in[10]; const float* Whh = (const float*)d_in[11];
  const float* bih = (const float*)d_in[12]; const float* bhh = (const float*)d_in[13];
  const float* W1 = (const float*)d_in[14];  const float* b1 = (const float*)d_in[15];
  const float* W2 = (const float*)d_in[16];  const float* b2 = (const float*)d_in[17];
  const float* lin_g = (const float*)d_in[18]; const float* lin_b = (const float*)d_in[19];
  const float* ls_g  = (const float*)d_in[20]; const float* ls_b  = (const float*)d_in[21];
  const float* lff_g = (const float*)d_in[22]; const float* lff_b = (const float*)d_in[23];

  float* slots = (float*)d_out;  // [B,S,D] lives in d_out, updated in place
  float* keys     = (float*)d_ws;                       // 33,554,432 f
  float* values   = keys + (size_t)B_ * N_ * D_;        // 33,554,432 f
  float* qbuf     = values + (size_t)B_ * N_ * D_;      // 57,344 f
  float* logits   = qbuf + (size_t)B_ * S_ * D_;        // 1,835,008 f
  float* partialA = logits + (size_t)B_ * S_ * N_;      // 458,752 f

  k_init<<<224, 256, 0, stream>>>(noise, mu, sigma, slots);
  k_lnkv<<<4096, 256, 0, stream>>>(emb, Wk, bk, Wv, bv, lin_g, lin_b, keys, values);
  for (int it = 0; it < ITERS_; it++) {
    k_q<<<448, 128, 0, stream>>>(slots, Wq, bq, ls_g, ls_b, qbuf);
    k_logits<<<512, 256, 0, stream>>>(qbuf, keys, logits);
    k_softmax<<<448, 256, 0, stream>>>(logits);
    k_updates<<<512, 256, 0, stream>>>(logits, values, partialA);
    k_gruff<<<448, 128, 0, stream>>>(partialA, slots, Wih, Whh, bih, bhh,
                                     W1, b1, W2, b2, lff_g, lff_b);
  }
}